// Round 4
// baseline (327.525 us; speedup 1.0000x reference)
//
#include <hip/hip_runtime.h>
#include <math.h>

// MarginLoss: out[b] = -relu(logits[b][label[b]] - max_{c != label[b]} logits[b][c])
// B=65536, C=1000 fp32. Pure streaming row-reduction, 262 MB read/launch.
// Persistent waves (8192), 8 rows/wave, prefetch distance 2: while row r is
// reduced, rows r+nw and r+2nw are in flight (8 outstanding dwordx4/lane).

typedef float v4 __attribute__((ext_vector_type(4)));

constexpr int C  = 1000;
constexpr int NV = 250;  // float4 per row

struct Row { v4 a, b, c, d; int lab; };

__device__ __forceinline__ void load_row(const float* __restrict__ logits,
                                         const int* __restrict__ label,
                                         int r, int lane, Row& R) {
    const v4* __restrict__ p = (const v4*)(logits + (size_t)r * C);
    R.a = __builtin_nontemporal_load(p + lane);
    R.b = __builtin_nontemporal_load(p + lane + 64);
    R.c = __builtin_nontemporal_load(p + lane + 128);
    if (lane + 192 < NV) {                       // lanes 0..57
        R.d = __builtin_nontemporal_load(p + lane + 192);
    } else {
        R.d = (v4){-INFINITY, -INFINITY, -INFINITY, -INFINITY};
    }
    R.lab = label[r];
}

__device__ __forceinline__ float row_result(const Row& R, int lane) {
    const int lab = R.lab;
    float m  = -INFINITY;   // max over non-label elements (this lane's slice)
    float lv = -INFINITY;   // label's logit (only the owning lane sets it)
    auto proc = [&](v4 v, int i) {
        const int dd = lab - (i << 2);
        if ((unsigned)dd < 4u) {   // cndmask selects
            lv = (dd == 0) ? v[0] : (dd == 1) ? v[1] : (dd == 2) ? v[2] : v[3];
            if (dd == 0)      v[0] = -INFINITY;
            else if (dd == 1) v[1] = -INFINITY;
            else if (dd == 2) v[2] = -INFINITY;
            else              v[3] = -INFINITY;
        }
        m = fmaxf(m, fmaxf(fmaxf(v[0], v[1]), fmaxf(v[2], v[3])));
    };
    // Tail lanes (i = lane+192 >= 250): dd < 0 so no label hit, and d == -inf.
    proc(R.a, lane); proc(R.b, lane + 64); proc(R.c, lane + 128); proc(R.d, lane + 192);

    const float lvs = __shfl(lv, (lab >> 2) & 63);  // broadcast from owner lane
    #pragma unroll
    for (int off = 32; off > 0; off >>= 1)
        m = fmaxf(m, __shfl_xor(m, off));
    return -fmaxf(lvs - m, 0.0f);  // MARGIN = 0
}

__global__ __launch_bounds__(256) void margin_loss_kernel(
    const float* __restrict__ logits,
    const int* __restrict__ label,
    float* __restrict__ out,
    int B, int nwaves)
{
    const int gwave = (blockIdx.x * blockDim.x + threadIdx.x) >> 6;
    const int lane  = threadIdx.x & 63;

    int r = gwave;
    if (r >= B) return;

    // Prologue: rows r and r+nw in flight.
    Row cur, nxt, nx2;
    load_row(logits, label, r, lane, cur);
    const int r1 = r + nwaves;
    if (r1 < B) load_row(logits, label, r1, lane, nxt);

    while (true) {
        const int rn  = r + nwaves;
        const int rn2 = r + 2 * nwaves;
        if (rn2 < B) load_row(logits, label, rn2, lane, nx2);

        const float res = row_result(cur, lane);
        if (lane == 0) out[r] = res;

        if (rn >= B) break;
        cur = nxt; nxt = nx2;
        r = rn;
    }
}

extern "C" void kernel_launch(void* const* d_in, const int* in_sizes, int n_in,
                              void* d_out, int out_size, void* d_ws, size_t ws_size,
                              hipStream_t stream)
{
    const float* logits = (const float*)d_in[0];
    const int*   label  = (const int*)d_in[1];
    float*       out    = (float*)d_out;

    const int B = out_size;  // 65536

    // Persistent waves: 8192 waves (2048 blocks x 4 waves) -> 8 rows per wave.
    int nwaves = 8192;
    if (nwaves > B) nwaves = B;
    const int rows_per_block = 256 / 64;
    const int grid = (nwaves + rows_per_block - 1) / rows_per_block;
    margin_loss_kernel<<<grid, 256, 0, stream>>>(logits, label, out, B, nwaves);
}

// Round 5
// 323.323 us; speedup vs baseline: 1.0130x; 1.0130x over previous
//
#include <hip/hip_runtime.h>
#include <math.h>

// MarginLoss: out[b] = -relu(logits[b][label[b]] - max_{c != label[b]} logits[b][c])
// B=65536, C=1000 fp32. Pure streaming row-reduction, 262 MB read/launch.
// Persistent waves: 8192 waves, 8 rows each, 2-stage software pipeline so the
// next row's 4x global_load_dwordx4 (nontemporal) are in flight while the
// current row is reduced. One wave per row-slice, 64-lane butterfly max.
// R4 post-mortem: prefetch distance 2 regressed (327.5 vs 320.3 us) -- extra
// live Row cost VGPRs/occupancy with nothing to gain (already 14x the
// in-flight bytes Little's law requires). This is the R3 prefetch-1 version.

typedef float v4 __attribute__((ext_vector_type(4)));

constexpr int C  = 1000;
constexpr int NV = 250;  // float4 per row

__device__ __forceinline__ void load_row(const v4* __restrict__ p, int lane,
                                         v4& a, v4& b, v4& c, v4& d) {
    a = __builtin_nontemporal_load(p + lane);
    b = __builtin_nontemporal_load(p + lane + 64);
    c = __builtin_nontemporal_load(p + lane + 128);
    if (lane + 192 < NV) {                       // lanes 0..57
        d = __builtin_nontemporal_load(p + lane + 192);
    } else {
        d = (v4){-INFINITY, -INFINITY, -INFINITY, -INFINITY};
    }
}

__device__ __forceinline__ float row_result(v4 a, v4 b, v4 c, v4 d,
                                            int lane, int lab) {
    float m  = -INFINITY;   // max over non-label elements (this lane's slice)
    float lv = -INFINITY;   // label's logit (only the owning lane sets it)
    auto proc = [&](v4 v, int i) {
        const int dd = lab - (i << 2);
        if ((unsigned)dd < 4u) {   // cndmask selects
            lv = (dd == 0) ? v[0] : (dd == 1) ? v[1] : (dd == 2) ? v[2] : v[3];
            if (dd == 0)      v[0] = -INFINITY;
            else if (dd == 1) v[1] = -INFINITY;
            else if (dd == 2) v[2] = -INFINITY;
            else              v[3] = -INFINITY;
        }
        m = fmaxf(m, fmaxf(fmaxf(v[0], v[1]), fmaxf(v[2], v[3])));
    };
    // Tail lanes (i=lane+192 >= 250): dd < 0 so no label hit, and d == -inf.
    proc(a, lane); proc(b, lane + 64); proc(c, lane + 128); proc(d, lane + 192);

    const float lvs = __shfl(lv, (lab >> 2) & 63);  // broadcast from owner lane
    #pragma unroll
    for (int off = 32; off > 0; off >>= 1)
        m = fmaxf(m, __shfl_xor(m, off));
    return -fmaxf(lvs - m, 0.0f);  // MARGIN = 0
}

__global__ __launch_bounds__(256) void margin_loss_kernel(
    const float* __restrict__ logits,
    const int* __restrict__ label,
    float* __restrict__ out,
    int B, int nwaves)
{
    const int gwave = (blockIdx.x * blockDim.x + threadIdx.x) >> 6;
    const int lane  = threadIdx.x & 63;

    int r = gwave;
    if (r >= B) return;

    // Prologue: issue row r's loads.
    v4 a, b, c, d;
    load_row((const v4*)(logits + (size_t)r * C), lane, a, b, c, d);
    int lab = label[r];

    while (true) {
        const int rn = r + nwaves;
        v4 an, bn, cn, dn;
        int labn = 0;
        if (rn < B) {
            // Issue next row's loads BEFORE reducing the current row:
            // latency overlaps the reduction below.
            load_row((const v4*)(logits + (size_t)rn * C), lane, an, bn, cn, dn);
            labn = label[rn];
        }

        const float res = row_result(a, b, c, d, lane, lab);
        if (lane == 0) out[r] = res;

        if (rn >= B) break;
        a = an; b = bn; c = cn; d = dn; lab = labn;
        r = rn;
    }
}

extern "C" void kernel_launch(void* const* d_in, const int* in_sizes, int n_in,
                              void* d_out, int out_size, void* d_ws, size_t ws_size,
                              hipStream_t stream)
{
    const float* logits = (const float*)d_in[0];
    const int*   label  = (const int*)d_in[1];
    float*       out    = (float*)d_out;

    const int B = out_size;  // 65536

    // Persistent waves: 8192 waves (2048 blocks x 4 waves) -> 8 rows per wave.
    int nwaves = 8192;
    if (nwaves > B) nwaves = B;
    const int rows_per_block = 256 / 64;
    const int grid = (nwaves + rows_per_block - 1) / rows_per_block;
    margin_loss_kernel<<<grid, 256, 0, stream>>>(logits, label, out, B, nwaves);
}